// Round 1
// baseline (1213.578 us; speedup 1.0000x reference)
//
#include <hip/hip_runtime.h>
#include <cstdint>

typedef unsigned short u16;
typedef __bf16 bf16x8 __attribute__((ext_vector_type(8)));
typedef float   f32x4 __attribute__((ext_vector_type(4)));
typedef u16     u16x8 __attribute__((ext_vector_type(8)));
typedef u16     u16x4 __attribute__((ext_vector_type(4)));

__device__ __forceinline__ u16 f2bf(float f) {
  union { float f; unsigned u; } v; v.f = f;
  unsigned r = (v.u + 0x7fffu + ((v.u >> 16) & 1u)) >> 16;
  return (u16)r;
}
__device__ __forceinline__ float bf2f(u16 h) {
  union { unsigned u; float f; } v; v.u = ((unsigned)h) << 16;
  return v.f;
}

// ---------------- transpose+convert fp32 [K][N] -> bf16 [N][K] ----------------
__global__ void k_trans4(const float* __restrict__ w0, const float* __restrict__ w1,
                         const float* __restrict__ w2, const float* __restrict__ w3,
                         u16* __restrict__ dst) {
  __shared__ u16 t[32][33];
  int z = blockIdx.z;
  const float* src = z == 0 ? w0 : z == 1 ? w1 : z == 2 ? w2 : w3;
  u16* d = dst + (size_t)z * 1024 * 1024;
  int k0 = blockIdx.x * 32, n0 = blockIdx.y * 32;
  int tx = threadIdx.x, ty = threadIdx.y;
#pragma unroll
  for (int i = 0; i < 4; i++) {
    int r = ty + i * 8;
    t[r][tx] = f2bf(src[(size_t)(k0 + r) * 1024 + n0 + tx]);
  }
  __syncthreads();
#pragma unroll
  for (int i = 0; i < 4; i++) {
    int r = ty + i * 8;
    d[(size_t)(n0 + r) * 1024 + k0 + tx] = t[tx][r];
  }
}

__global__ void k_trans_exp(const float* __restrict__ pe, const float* __restrict__ ps,
                            u16* __restrict__ dst, int K, int N) {
  __shared__ u16 t[32][33];
  int z = blockIdx.z;
  size_t msz = (size_t)K * N;
  const float* src = z < 8 ? pe + (size_t)z * msz : ps + (size_t)(z - 8) * msz;
  u16* d = dst + (size_t)z * msz;
  int k0 = blockIdx.x * 32, n0 = blockIdx.y * 32;
  int tx = threadIdx.x, ty = threadIdx.y;
#pragma unroll
  for (int i = 0; i < 4; i++) {
    int r = ty + i * 8;
    t[r][tx] = f2bf(src[(size_t)(k0 + r) * N + n0 + tx]);
  }
  __syncthreads();
#pragma unroll
  for (int i = 0; i < 4; i++) {
    int r = ty + i * 8;
    d[(size_t)(n0 + r) * K + k0 + tx] = t[tx][r];
  }
}

__global__ void k_bias(const float* __restrict__ be1, const float* __restrict__ bs1,
                       const float* __restrict__ be2, const float* __restrict__ bs2,
                       float* __restrict__ b1a, float* __restrict__ b2a) {
  int i = blockIdx.x * 256 + threadIdx.x;
  if (i < 40960) b1a[i] = i < 32768 ? be1[i] : bs1[i - 32768];
  else {
    int j = i - 40960;
    if (j < 10240) b2a[j] = j < 8192 ? be2[j] : bs2[j - 8192];
  }
}

// ---------------- layernorm (row of 1024), writes bf16 (+ optional fp32) -----
__global__ __launch_bounds__(256) void k_ln(const float* __restrict__ x,
                                            const float* __restrict__ g,
                                            const float* __restrict__ b,
                                            u16* __restrict__ outb,
                                            float* __restrict__ outf) {
  int row = blockIdx.x, tid = threadIdx.x;
  const float* xr = x + (size_t)row * 1024;
  float4 v = *(const float4*)(xr + tid * 4);
  float s1 = v.x + v.y + v.z + v.w;
  float s2 = v.x * v.x + v.y * v.y + v.z * v.z + v.w * v.w;
#pragma unroll
  for (int o = 32; o; o >>= 1) { s1 += __shfl_down(s1, o); s2 += __shfl_down(s2, o); }
  __shared__ float r1[4], r2[4], mv[2];
  int wave = tid >> 6;
  if ((tid & 63) == 0) { r1[wave] = s1; r2[wave] = s2; }
  __syncthreads();
  if (tid == 0) {
    float a = r1[0] + r1[1] + r1[2] + r1[3];
    float q = r2[0] + r2[1] + r2[2] + r2[3];
    float mean = a * (1.f / 1024.f);
    float var = q * (1.f / 1024.f) - mean * mean;
    mv[0] = mean; mv[1] = rsqrtf(var + 1e-5f);
  }
  __syncthreads();
  float mean = mv[0], inv = mv[1];
  int c = tid * 4;
  float4 gg = *(const float4*)(g + c);
  float4 bb = *(const float4*)(b + c);
  float o0 = (v.x - mean) * inv * gg.x + bb.x;
  float o1 = (v.y - mean) * inv * gg.y + bb.y;
  float o2 = (v.z - mean) * inv * gg.z + bb.z;
  float o3 = (v.w - mean) * inv * gg.w + bb.w;
  u16x4 h4 = { f2bf(o0), f2bf(o1), f2bf(o2), f2bf(o3) };
  *(u16x4*)(outb + (size_t)row * 1024 + c) = h4;
  if (outf) {
    float4 of = { o0, o1, o2, o3 };
    *(float4*)(outf + (size_t)row * 1024 + c) = of;
  }
}

// ---------------- bf16 MFMA GEMM: A[M][K] x B[N][K] -> out[M][N] -------------
// EPI: 0 = +bias -> bf16 ; 1 = +bias +res -> f32 ; 2 = gelu(+bias) -> bf16 ; 3 = +bias -> f32
#define TM 128
#define TN 128
#define BKK 64
#define LDKK 72

template<int EPI, bool GROUPED, bool GATHER>
__global__ __launch_bounds__(256, 2)
void k_gemm(const u16* __restrict__ A, const u16* __restrict__ Ball,
            const float* __restrict__ ball, void* __restrict__ outp,
            const float* __restrict__ res, int N, int K,
            const int* __restrict__ tmap, const int* __restrict__ stok) {
  int mtile = blockIdx.x, ntile = blockIdx.y;
  const u16* Bp = Ball;
  const float* bias = ball;
  if (GROUPED) {
    int e = tmap[mtile];
    if (e < 0) return;
    Bp = Ball + (size_t)e * N * K;
    bias = ball + (size_t)e * N;
  }
  __shared__ u16 As[TM][LDKK];
  __shared__ u16 Bs[TN][LDKK];
  __shared__ int rows[TM];
  int tid = threadIdx.x;
  if (GATHER) {
    if (tid < TM) rows[tid] = stok[mtile * TM + tid];
  }
  __syncthreads();
  int lane = tid & 63, wave = tid >> 6;
  int wm = (wave >> 1) * 64, wn = (wave & 1) * 64;
  int lm = lane & 15, lq = lane >> 4;
  f32x4 acc[4][4];
#pragma unroll
  for (int i = 0; i < 4; i++)
#pragma unroll
    for (int j = 0; j < 4; j++)
#pragma unroll
      for (int r = 0; r < 4; r++) acc[i][j][r] = 0.f;

  for (int k0 = 0; k0 < K; k0 += BKK) {
#pragma unroll
    for (int c = tid; c < TM * BKK / 8; c += 256) {
      int row = c >> 3, kc8 = (c & 7) << 3;
      size_t grow = GATHER ? (size_t)rows[row] : (size_t)mtile * TM + row;
      u16x8 vA = *(const u16x8*)(A + grow * K + k0 + kc8);
      *(u16x8*)&As[row][kc8] = vA;
      size_t gcol = (size_t)ntile * TN + row;
      u16x8 vB = *(const u16x8*)(Bp + gcol * K + k0 + kc8);
      *(u16x8*)&Bs[row][kc8] = vB;
    }
    __syncthreads();
#pragma unroll
    for (int ks = 0; ks < BKK; ks += 32) {
      bf16x8 af[4], bg[4];
#pragma unroll
      for (int i = 0; i < 4; i++) af[i] = *(const bf16x8*)&As[wm + i * 16 + lm][ks + lq * 8];
#pragma unroll
      for (int j = 0; j < 4; j++) bg[j] = *(const bf16x8*)&Bs[wn + j * 16 + lm][ks + lq * 8];
#pragma unroll
      for (int i = 0; i < 4; i++)
#pragma unroll
        for (int j = 0; j < 4; j++)
          acc[i][j] = __builtin_amdgcn_mfma_f32_16x16x32_bf16(af[i], bg[j], acc[i][j], 0, 0, 0);
    }
    __syncthreads();
  }

  size_t mbase = (size_t)mtile * TM;
#pragma unroll
  for (int i = 0; i < 4; i++) {
#pragma unroll
    for (int j = 0; j < 4; j++) {
      int rbase = wm + i * 16 + lq * 4;
      int col = ntile * TN + wn + j * 16 + lm;
      float bv = bias[col];
#pragma unroll
      for (int r = 0; r < 4; r++) {
        size_t grow = mbase + rbase + r;
        float v = acc[i][j][r] + bv;
        size_t off = grow * (size_t)N + col;
        if (EPI == 0) ((u16*)outp)[off] = f2bf(v);
        else if (EPI == 1) ((float*)outp)[off] = v + res[off];
        else if (EPI == 2) {
          float gl = 0.5f * v * (1.0f + erff(v * 0.70710678118f));
          ((u16*)outp)[off] = f2bf(gl);
        } else ((float*)outp)[off] = v;
      }
    }
  }
}

// ---------------- rope + latent compress (q,k rope'd; v plain) ---------------
__global__ __launch_bounds__(256) void k_ropec(
    const u16* __restrict__ qb, const u16* __restrict__ kb, const u16* __restrict__ vb,
    const float* __restrict__ cosb, const float* __restrict__ sinb,
    const float* __restrict__ Wqc, const float* __restrict__ bqc,
    const float* __restrict__ Wkc, const float* __restrict__ bkc,
    const float* __restrict__ Wvc, const float* __restrict__ bvc,
    float* __restrict__ qc, float* __restrict__ kc, float* __restrict__ vc) {
  int z = blockIdx.z;
  int t = blockIdx.x * 256 + threadIdx.x;
  int r = t >> 4, j = t & 15;
  int bh = r >> 10, l = r & 1023;
  int b = bh >> 4, h = bh & 15;
  const u16* src = z == 0 ? qb : z == 1 ? kb : vb;
  const float* W = z == 0 ? Wqc : z == 1 ? Wkc : Wvc;
  const float* bi = z == 0 ? bqc : z == 1 ? bkc : bvc;
  float* dst = z == 0 ? qc : z == 1 ? kc : vc;
  size_t ib = ((size_t)(b * 1024 + l)) * 1024 + h * 64;
  float acc = bi[j];
  if (z < 2) {
#pragma unroll
    for (int i = 0; i < 32; i++) {
      float te = bf2f(src[ib + 2 * i]), to = bf2f(src[ib + 2 * i + 1]);
      float c = cosb[l * 32 + i], s = sinb[l * 32 + i];
      float re = te * c - to * s, ro = te * s + to * c;
      acc += re * W[(2 * i) * 16 + j] + ro * W[(2 * i + 1) * 16 + j];
    }
  } else {
#pragma unroll
    for (int d = 0; d < 64; d++) acc += bf2f(src[ib + d]) * W[d * 16 + j];
  }
  dst[((size_t)bh * 1024 + l) * 16 + j] = acc;
}

// ---------------- flash attention over latent dim 16 -------------------------
__global__ __launch_bounds__(256) void k_attn(
    const float* __restrict__ qc, const float* __restrict__ kc, const float* __restrict__ vc,
    const float* __restrict__ Wdc, const float* __restrict__ bdc, u16* __restrict__ ao) {
  __shared__ float kcs[128][16], vcs[128][16];
  int bh = blockIdx.y;
  int r = blockIdx.x * 256 + threadIdx.x;
  const float* qrow = qc + ((size_t)bh * 1024 + r) * 16;
  float q[16];
#pragma unroll
  for (int c = 0; c < 16; c += 4) {
    float4 v = *(const float4*)(qrow + c);
    q[c] = v.x; q[c + 1] = v.y; q[c + 2] = v.z; q[c + 3] = v.w;
  }
  float m = -1e30f, lsum = 0.f, acc[16];
#pragma unroll
  for (int c = 0; c < 16; c++) acc[c] = 0.f;
  int jmax = blockIdx.x * 256 + 255;
  for (int j0 = 0; j0 <= jmax; j0 += 128) {
    __syncthreads();
    for (int i = threadIdx.x; i < 512; i += 256) {
      int jr = i >> 2, c4 = (i & 3) << 2;
      size_t sb = ((size_t)bh * 1024 + j0 + jr) * 16 + c4;
      *(float4*)&kcs[jr][c4] = *(const float4*)(kc + sb);
      *(float4*)&vcs[jr][c4] = *(const float4*)(vc + sb);
    }
    __syncthreads();
    int jend = min(128, r - j0 + 1);
    for (int j = 0; j < jend; j++) {
      float s = 0.f;
#pragma unroll
      for (int c = 0; c < 16; c++) s += q[c] * kcs[j][c];
      s *= 0.25f;
      if (s > m) {
        float sc = __expf(m - s);
        m = s; lsum *= sc;
#pragma unroll
        for (int c = 0; c < 16; c++) acc[c] *= sc;
      }
      float p = __expf(s - m);
      lsum += p;
#pragma unroll
      for (int c = 0; c < 16; c++) acc[c] += p * vcs[j][c];
    }
  }
  float inv = 1.f / lsum;
#pragma unroll
  for (int c = 0; c < 16; c++) acc[c] *= inv;
  int b = bh >> 4, h = bh & 15;
  size_t ob = ((size_t)(b * 1024 + r)) * 1024 + h * 64;
#pragma unroll
  for (int d = 0; d < 64; d++) {
    float s = bdc[d];
#pragma unroll
    for (int c = 0; c < 16; c++) s += acc[c] * Wdc[c * 64 + d];
    ao[ob + d] = f2bf(s);
  }
}

// ---------------- router gates + top-2 ---------------------------------------
__global__ __launch_bounds__(256) void k_gates(const float* __restrict__ h2f,
                                               const float* __restrict__ Wr,
                                               const float* __restrict__ br,
                                               int* __restrict__ eidx,
                                               float* __restrict__ ew) {
  int n = blockIdx.x, tid = threadIdx.x;
  int e = tid >> 5, i = tid & 31;
  const float* hr = h2f + (size_t)n * 1024;
  float s = 0.f;
  for (int d = i; d < 1024; d += 32) s += hr[d] * Wr[d * 8 + e];
#pragma unroll
  for (int o = 16; o; o >>= 1) s += __shfl_down(s, o, 32);
  __shared__ float gate[8];
  if (i == 0) gate[e] = s + br[e];
  __syncthreads();
  if (tid == 0) {
    float v0 = -1e30f, v1 = -1e30f; int i0 = 0, i1 = 0;
#pragma unroll
    for (int ee = 0; ee < 8; ee++) {
      float gv = gate[ee];
      if (gv > v0) { v1 = v0; i1 = i0; v0 = gv; i0 = ee; }
      else if (gv > v1) { v1 = gv; i1 = ee; }
    }
    float p0 = 1.f / (1.f + expf(v1 - v0));
    eidx[2 * n] = i0; eidx[2 * n + 1] = i1;
    ew[2 * n] = p0; ew[2 * n + 1] = 1.f - p0;
  }
}

// ---------------- routing: counting sort by expert, padded to 128 ------------
__global__ void k_route(const int* __restrict__ eidx, int* __restrict__ stok,
                        int* __restrict__ posA, int* __restrict__ tmap) {
  __shared__ int cnt[8], base[8], cur[8];
  int tid = threadIdx.x;
  if (tid < 8) { cnt[tid] = 0; cur[tid] = 0; }
  __syncthreads();
  for (int a = tid; a < 4096; a += 256) atomicAdd(&cnt[eidx[a]], 1);
  __syncthreads();
  if (tid == 0) {
    for (int tt = 0; tt < 16; tt++) tmap[tt] = 8;
    for (int tt = 16; tt < 32; tt++) tmap[tt] = 9;
    int off = 4096, t = 32;
    for (int e = 0; e < 8; e++) {
      base[e] = off;
      int nt = (cnt[e] + 127) >> 7;
      for (int k = 0; k < nt; k++) tmap[t++] = e;
      off += nt * 128;
    }
    for (; t < 72; t++) tmap[t] = -1;
  }
  __syncthreads();
  for (int r = tid; r < 4096; r += 256) stok[r] = r & 2047;
  for (int r = 4096 + tid; r < 9216; r += 256) stok[r] = 0;
  __syncthreads();
  for (int a = tid; a < 4096; a += 256) {
    int e = eidx[a];
    int p = base[e] + atomicAdd(&cur[e], 1);
    stok[p] = a >> 1;
    posA[a] = p;
  }
}

// ---------------- final combine: x2 + shared mean + weighted moe -------------
__global__ __launch_bounds__(256) void k_combine(const float* __restrict__ x2,
                                                 const float* __restrict__ oe,
                                                 const int* __restrict__ posA,
                                                 const float* __restrict__ ew,
                                                 float* __restrict__ out) {
  int n = blockIdx.x, tid = threadIdx.x;
  int c = tid * 4;
  int p0 = posA[2 * n], p1 = posA[2 * n + 1];
  float w0 = ew[2 * n], w1 = ew[2 * n + 1];
  size_t bidx = (size_t)n * 1024 + c;
  float4 r = *(const float4*)(x2 + bidx);
  float4 s0 = *(const float4*)(oe + bidx);
  float4 s1 = *(const float4*)(oe + (size_t)(2048 + n) * 1024 + c);
  float4 m0 = *(const float4*)(oe + (size_t)p0 * 1024 + c);
  float4 m1 = *(const float4*)(oe + (size_t)p1 * 1024 + c);
  float4 o;
  o.x = r.x + 0.5f * (s0.x + s1.x) + w0 * m0.x + w1 * m1.x;
  o.y = r.y + 0.5f * (s0.y + s1.y) + w0 * m0.y + w1 * m1.y;
  o.z = r.z + 0.5f * (s0.z + s1.z) + w0 * m0.z + w1 * m1.z;
  o.w = r.w + 0.5f * (s0.w + s1.w) + w0 * m0.w + w1 * m1.w;
  *(float4*)(out + bidx) = o;
}

// =============================================================================
extern "C" void kernel_launch(void* const* d_in, const int* in_sizes, int n_in,
                              void* d_out, int out_size, void* d_ws, size_t ws_size,
                              hipStream_t stream) {
  const float* x    = (const float*)d_in[0];
  const float* cosb = (const float*)d_in[1];
  const float* sinb = (const float*)d_in[2];
  const float* ln1g = (const float*)d_in[3];
  const float* ln1b = (const float*)d_in[4];
  const float* Wq   = (const float*)d_in[5];
  const float* bq   = (const float*)d_in[6];
  const float* Wk   = (const float*)d_in[7];
  const float* bk   = (const float*)d_in[8];
  const float* Wv   = (const float*)d_in[9];
  const float* bv   = (const float*)d_in[10];
  const float* Wqc  = (const float*)d_in[11];
  const float* bqc  = (const float*)d_in[12];
  const float* Wkc  = (const float*)d_in[13];
  const float* bkc  = (const float*)d_in[14];
  const float* Wvc  = (const float*)d_in[15];
  const float* bvc  = (const float*)d_in[16];
  const float* Wdc  = (const float*)d_in[17];
  const float* bdc  = (const float*)d_in[18];
  const float* Wo   = (const float*)d_in[19];
  const float* bo   = (const float*)d_in[20];
  const float* ln2g = (const float*)d_in[21];
  const float* ln2b = (const float*)d_in[22];
  const float* Wr   = (const float*)d_in[23];
  const float* br   = (const float*)d_in[24];
  const float* We1  = (const float*)d_in[25];
  const float* be1  = (const float*)d_in[26];
  const float* We2  = (const float*)d_in[27];
  const float* be2  = (const float*)d_in[28];
  const float* Ws1  = (const float*)d_in[29];
  const float* bs1  = (const float*)d_in[30];
  const float* Ws2  = (const float*)d_in[31];
  const float* bs2  = (const float*)d_in[32];

  char* w = (char*)d_ws;
  size_t off = 0;
  auto alloc = [&](size_t bytes) -> void* {
    off = (off + 255) & ~(size_t)255;
    void* p = w + off;
    off += bytes;
    return p;
  };
  u16*   WT   = (u16*)alloc(4ull * 1024 * 1024 * 2);
  u16*   W1a  = (u16*)alloc(10ull * 4096 * 1024 * 2);
  u16*   W2a  = (u16*)alloc(10ull * 4096 * 1024 * 2);
  float* b1a  = (float*)alloc(10 * 4096 * 4);
  float* b2a  = (float*)alloc(10 * 1024 * 4);
  u16*   hbuf = (u16*)alloc(2048ull * 1024 * 2);
  u16*   qb   = (u16*)alloc(2048ull * 1024 * 2);
  u16*   kb   = (u16*)alloc(2048ull * 1024 * 2);
  u16*   vb   = (u16*)alloc(2048ull * 1024 * 2);
  float* qcb  = (float*)alloc(32768ull * 16 * 4);
  float* kcb  = (float*)alloc(32768ull * 16 * 4);
  float* vcb  = (float*)alloc(32768ull * 16 * 4);
  u16*   aob  = (u16*)alloc(2048ull * 1024 * 2);
  float* x2b  = (float*)alloc(2048ull * 1024 * 4);
  u16*   h2b  = (u16*)alloc(2048ull * 1024 * 2);
  float* h2f  = (float*)alloc(2048ull * 1024 * 4);
  int*   eidx = (int*)alloc(4096 * 4);
  float* ew   = (float*)alloc(4096 * 4);
  int*   posA = (int*)alloc(4096 * 4);
  int*   stok = (int*)alloc(9216 * 4);
  int*   tmap = (int*)alloc(72 * 4);
  u16*   heb  = (u16*)alloc(9216ull * 4096 * 2);
  float* oeb  = (float*)alloc(9216ull * 1024 * 4);
  (void)ws_size; (void)in_sizes; (void)n_in; (void)out_size;

  // weight conversion (re-done every call: harness re-poisons ws)
  k_trans4   <<<dim3(32, 32, 4),  dim3(32, 8), 0, stream>>>(Wq, Wk, Wv, Wo, WT);
  k_trans_exp<<<dim3(32, 128, 10), dim3(32, 8), 0, stream>>>(We1, Ws1, W1a, 1024, 4096);
  k_trans_exp<<<dim3(128, 32, 10), dim3(32, 8), 0, stream>>>(We2, Ws2, W2a, 4096, 1024);
  k_bias     <<<200, 256, 0, stream>>>(be1, bs1, be2, bs2, b1a, b2a);

  // attention path
  k_ln<<<2048, 256, 0, stream>>>(x, ln1g, ln1b, hbuf, nullptr);
  k_gemm<0, false, false><<<dim3(16, 8), 256, 0, stream>>>(hbuf, WT,                bq, qb, nullptr, 1024, 1024, nullptr, nullptr);
  k_gemm<0, false, false><<<dim3(16, 8), 256, 0, stream>>>(hbuf, WT + 1048576,      bk, kb, nullptr, 1024, 1024, nullptr, nullptr);
  k_gemm<0, false, false><<<dim3(16, 8), 256, 0, stream>>>(hbuf, WT + 2097152,      bv, vb, nullptr, 1024, 1024, nullptr, nullptr);
  k_ropec<<<dim3(2048, 1, 3), 256, 0, stream>>>(qb, kb, vb, cosb, sinb,
                                                Wqc, bqc, Wkc, bkc, Wvc, bvc, qcb, kcb, vcb);
  k_attn<<<dim3(4, 32), 256, 0, stream>>>(qcb, kcb, vcb, Wdc, bdc, aob);
  k_gemm<1, false, false><<<dim3(16, 8), 256, 0, stream>>>(aob, WT + 3145728, bo, x2b, x, 1024, 1024, nullptr, nullptr);

  // FFN path
  k_ln<<<2048, 256, 0, stream>>>(x2b, ln2g, ln2b, h2b, h2f);
  k_gates<<<2048, 256, 0, stream>>>(h2f, Wr, br, eidx, ew);
  k_route<<<1, 256, 0, stream>>>(eidx, stok, posA, tmap);
  k_gemm<2, true, true ><<<dim3(72, 32), 256, 0, stream>>>(h2b, W1a, b1a, heb, nullptr, 4096, 1024, tmap, stok);
  k_gemm<3, true, false><<<dim3(72, 8),  256, 0, stream>>>(heb, W2a, b2a, oeb, nullptr, 1024, 4096, tmap, nullptr);
  k_combine<<<2048, 256, 0, stream>>>(x2b, oeb, posA, ew, (float*)d_out);
}

// Round 3
// 1014.338 us; speedup vs baseline: 1.1964x; 1.1964x over previous
//
#include <hip/hip_runtime.h>
#include <cstdint>

typedef unsigned short u16;
typedef unsigned int u32;
typedef __bf16 bf16x8 __attribute__((ext_vector_type(8)));
typedef float   f32x4 __attribute__((ext_vector_type(4)));
typedef u16     u16x8 __attribute__((ext_vector_type(8)));
typedef u16     u16x4 __attribute__((ext_vector_type(4)));

#define AS1 __attribute__((address_space(1)))
#define AS3 __attribute__((address_space(3)))

__device__ __forceinline__ void gload_lds16(const void* g, void* l) {
  __builtin_amdgcn_global_load_lds((const AS1 void*)g, (AS3 void*)l, 16, 0, 0);
}

__device__ __forceinline__ u16 f2bf(float f) {
  union { float f; unsigned u; } v; v.f = f;
  unsigned r = (v.u + 0x7fffu + ((v.u >> 16) & 1u)) >> 16;
  return (u16)r;
}
__device__ __forceinline__ float bf2f(u16 h) {
  union { unsigned u; float f; } v; v.u = ((unsigned)h) << 16;
  return v.f;
}

// ---------------- transpose+convert fp32 [K][N] -> bf16 [N][K] ----------------
__global__ void k_trans4(const float* __restrict__ w0, const float* __restrict__ w1,
                         const float* __restrict__ w2, const float* __restrict__ w3,
                         u16* __restrict__ dst) {
  __shared__ u16 t[32][33];
  int z = blockIdx.z;
  const float* src = z == 0 ? w0 : z == 1 ? w1 : z == 2 ? w2 : w3;
  u16* d = dst + (size_t)z * 1024 * 1024;
  int k0 = blockIdx.x * 32, n0 = blockIdx.y * 32;
  int tx = threadIdx.x, ty = threadIdx.y;
#pragma unroll
  for (int i = 0; i < 4; i++) {
    int r = ty + i * 8;
    t[r][tx] = f2bf(src[(size_t)(k0 + r) * 1024 + n0 + tx]);
  }
  __syncthreads();
#pragma unroll
  for (int i = 0; i < 4; i++) {
    int r = ty + i * 8;
    d[(size_t)(n0 + r) * 1024 + k0 + tx] = t[tx][r];
  }
}

__global__ void k_trans_exp(const float* __restrict__ pe, const float* __restrict__ ps,
                            u16* __restrict__ dst, int K, int N) {
  __shared__ u16 t[32][33];
  int z = blockIdx.z;
  size_t msz = (size_t)K * N;
  const float* src = z < 8 ? pe + (size_t)z * msz : ps + (size_t)(z - 8) * msz;
  u16* d = dst + (size_t)z * msz;
  int k0 = blockIdx.x * 32, n0 = blockIdx.y * 32;
  int tx = threadIdx.x, ty = threadIdx.y;
#pragma unroll
  for (int i = 0; i < 4; i++) {
    int r = ty + i * 8;
    t[r][tx] = f2bf(src[(size_t)(k0 + r) * N + n0 + tx]);
  }
  __syncthreads();
#pragma unroll
  for (int i = 0; i < 4; i++) {
    int r = ty + i * 8;
    d[(size_t)(n0 + r) * K + k0 + tx] = t[tx][r];
  }
}

__global__ void k_bias(const float* __restrict__ be1, const float* __restrict__ bs1,
                       const float* __restrict__ be2, const float* __restrict__ bs2,
                       const float* __restrict__ bq, const float* __restrict__ bk,
                       const float* __restrict__ bv,
                       float* __restrict__ b1a, float* __restrict__ b2a,
                       float* __restrict__ bqkv) {
  int i = blockIdx.x * 256 + threadIdx.x;
  if (i < 32768) b1a[i] = be1[i];
  else if (i < 40960) b1a[i] = bs1[i - 32768];
  else if (i < 49152) b2a[i - 40960] = be2[i - 40960];
  else if (i < 51200) b2a[i - 40960] = bs2[i - 49152];
  else if (i < 52224) bqkv[i - 51200] = bq[i - 51200];
  else if (i < 53248) bqkv[i - 51200] = bk[i - 52224];
  else if (i < 54272) bqkv[i - 51200] = bv[i - 53248];
}

// ---------------- layernorm (row of 1024), writes bf16 (+ optional fp32) -----
__global__ __launch_bounds__(256) void k_ln(const float* __restrict__ x,
                                            const float* __restrict__ g,
                                            const float* __restrict__ b,
                                            u16* __restrict__ outb,
                                            float* __restrict__ outf) {
  int row = blockIdx.x, tid = threadIdx.x;
  const float* xr = x + (size_t)row * 1024;
  float4 v = *(const float4*)(xr + tid * 4);
  float s1 = v.x + v.y + v.z + v.w;
  float s2 = v.x * v.x + v.y * v.y + v.z * v.z + v.w * v.w;
#pragma unroll
  for (int o = 32; o; o >>= 1) { s1 += __shfl_down(s1, o); s2 += __shfl_down(s2, o); }
  __shared__ float r1[4], r2[4], mv[2];
  int wave = tid >> 6;
  if ((tid & 63) == 0) { r1[wave] = s1; r2[wave] = s2; }
  __syncthreads();
  if (tid == 0) {
    float a = r1[0] + r1[1] + r1[2] + r1[3];
    float q = r2[0] + r2[1] + r2[2] + r2[3];
    float mean = a * (1.f / 1024.f);
    float var = q * (1.f / 1024.f) - mean * mean;
    mv[0] = mean; mv[1] = rsqrtf(var + 1e-5f);
  }
  __syncthreads();
  float mean = mv[0], inv = mv[1];
  int c = tid * 4;
  float4 gg = *(const float4*)(g + c);
  float4 bb = *(const float4*)(b + c);
  float o0 = (v.x - mean) * inv * gg.x + bb.x;
  float o1 = (v.y - mean) * inv * gg.y + bb.y;
  float o2 = (v.z - mean) * inv * gg.z + bb.z;
  float o3 = (v.w - mean) * inv * gg.w + bb.w;
  u16x4 h4 = { f2bf(o0), f2bf(o1), f2bf(o2), f2bf(o3) };
  *(u16x4*)(outb + (size_t)row * 1024 + c) = h4;
  if (outf) {
    float4 of = { o0, o1, o2, o3 };
    *(float4*)(outf + (size_t)row * 1024 + c) = of;
  }
}

// ---------------- bf16 MFMA GEMM: A[M][K] x B[N][K] -> out[M][N] -------------
// global_load_lds width-16 staging (m97 pattern); LDS tiles UNPADDED (DMA is
// wave-uniform base + lane*16B, so layout must match lane order exactly).
// EPI: 0 = +bias -> bf16 ; 1 = +bias +res -> f32 ; 2 = gelu(+bias) -> bf16 ; 3 = +bias -> f32
#define TM 128
#define TN 128
#define BKK 64

template<int EPI, bool GROUPED, bool GATHER>
__global__ __launch_bounds__(256, 2)
void k_gemm(const u16* __restrict__ A, const u16* __restrict__ Ball,
            const float* __restrict__ ball, void* __restrict__ outp,
            const float* __restrict__ res, int N, int K,
            const int* __restrict__ tmap, const int* __restrict__ stok) {
  int mtile = blockIdx.x, ntile = blockIdx.y;
  const u16* Bp = Ball;
  const float* bias = ball;
  if (GROUPED) {
    int e = tmap[mtile];
    if (e < 0) return;
    Bp = Ball + (size_t)e * N * K;
    bias = ball + (size_t)e * N;
  }
  __shared__ u16 As[TM][BKK];
  __shared__ u16 Bs[TN][BKK];
  __shared__ int rows[TM];
  int tid = threadIdx.x;
  int lane = tid & 63, wave = tid >> 6;
  if (GATHER && tid < TM) rows[tid] = stok[mtile * TM + tid];
  __syncthreads();

  // staging geometry: one wave-issue covers 8 rows x 64 cols (8 lanes/row x 16B)
  int srow = lane >> 3;          // row within 8-row chunk
  int scol = (lane & 7) << 3;    // elem col, step 8 (16B)
  const u16* gA[4]; const u16* gB[4];
#pragma unroll
  for (int c = 0; c < 4; c++) {
    int row = wave * 32 + c * 8 + srow;
    size_t grow = GATHER ? (size_t)rows[row] : (size_t)mtile * TM + row;
    gA[c] = A + grow * K + scol;
    gB[c] = Bp + ((size_t)ntile * TN + row) * K + scol;
  }

  int wm = (wave >> 1) * 64, wn = (wave & 1) * 64;
  int lm = lane & 15, lq = lane >> 4;
  f32x4 acc[4][4];
#pragma unroll
  for (int i = 0; i < 4; i++)
#pragma unroll
    for (int j = 0; j < 4; j++)
#pragma unroll
      for (int r = 0; r < 4; r++) acc[i][j][r] = 0.f;

  for (int k0 = 0; k0 < K; k0 += BKK) {
#pragma unroll
    for (int c = 0; c < 4; c++) {
      gload_lds16(gA[c] + k0, &As[wave * 32 + c * 8][0]);
      gload_lds16(gB[c] + k0, &Bs[wave * 32 + c * 8][0]);
    }
    __builtin_amdgcn_s_waitcnt(0);  // explicit full drain (insurance; compiler
                                    // normally emits vmcnt(0) before s_barrier)
    __syncthreads();
#pragma unroll
    for (int ks = 0; ks < BKK; ks += 32) {
      bf16x8 af[4], bg[4];
#pragma unroll
      for (int i = 0; i < 4; i++) af[i] = *(const bf16x8*)&As[wm + i * 16 + lm][ks + lq * 8];
#pragma unroll
      for (int j = 0; j < 4; j++) bg[j] = *(const bf16x8*)&Bs[wn + j * 16 + lm][ks + lq * 8];
#pragma unroll
      for (int i = 0; i < 4; i++)
#pragma unroll
        for (int j = 0; j < 4; j++)
          acc[i][j] = __builtin_amdgcn_mfma_f32_16x16x32_bf16(af[i], bg[j], acc[i][j], 0, 0, 0);
    }
    __syncthreads();
  }

  size_t mbase = (size_t)mtile * TM;
#pragma unroll
  for (int i = 0; i < 4; i++) {
#pragma unroll
    for (int j = 0; j < 4; j++) {
      int rbase = wm + i * 16 + lq * 4;
      int col = ntile * TN + wn + j * 16 + lm;
      float bv = bias[col];
#pragma unroll
      for (int r = 0; r < 4; r++) {
        size_t grow = mbase + rbase + r;
        float v = acc[i][j][r] + bv;
        size_t off = grow * (size_t)N + col;
        if (EPI == 0) ((u16*)outp)[off] = f2bf(v);
        else if (EPI == 1) ((float*)outp)[off] = v + res[off];
        else if (EPI == 2) {
          float gl = 0.5f * v * (1.0f + erff(v * 0.70710678118f));
          ((u16*)outp)[off] = f2bf(gl);
        } else ((float*)outp)[off] = v;
      }
    }
  }
}

// ---------------- rope + latent compress (q,k rope'd; v plain) ---------------
// reads fused qkv buffer [2048][3072] bf16
__global__ __launch_bounds__(256) void k_ropec(
    const u16* __restrict__ qkvb,
    const float* __restrict__ cosb, const float* __restrict__ sinb,
    const float* __restrict__ Wqc, const float* __restrict__ bqc,
    const float* __restrict__ Wkc, const float* __restrict__ bkc,
    const float* __restrict__ Wvc, const float* __restrict__ bvc,
    float* __restrict__ qc, float* __restrict__ kc, float* __restrict__ vc) {
  int z = blockIdx.z;
  int t = blockIdx.x * 256 + threadIdx.x;
  int r = t >> 4, j = t & 15;
  int bh = r >> 10, l = r & 1023;
  int b = bh >> 4, h = bh & 15;
  const float* W = z == 0 ? Wqc : z == 1 ? Wkc : Wvc;
  const float* bi = z == 0 ? bqc : z == 1 ? bkc : bvc;
  float* dst = z == 0 ? qc : z == 1 ? kc : vc;
  const u16* src = qkvb + (size_t)(b * 1024 + l) * 3072 + z * 1024 + h * 64;
  float acc = bi[j];
  if (z < 2) {
#pragma unroll
    for (int i = 0; i < 32; i++) {
      float te = bf2f(src[2 * i]), to = bf2f(src[2 * i + 1]);
      float c = cosb[l * 32 + i], s = sinb[l * 32 + i];
      float re = te * c - to * s, ro = te * s + to * c;
      acc += re * W[(2 * i) * 16 + j] + ro * W[(2 * i + 1) * 16 + j];
    }
  } else {
#pragma unroll
    for (int d = 0; d < 64; d++) acc += bf2f(src[d]) * W[d * 16 + j];
  }
  dst[((size_t)bh * 1024 + l) * 16 + j] = acc;
}

// ---------------- flash attention over latent dim 16 -------------------------
__global__ __launch_bounds__(256) void k_attn(
    const float* __restrict__ qc, const float* __restrict__ kc, const float* __restrict__ vc,
    const float* __restrict__ Wdc, const float* __restrict__ bdc, u16* __restrict__ ao) {
  __shared__ float kcs[128][16], vcs[128][16];
  int bh = blockIdx.y;
  int r = blockIdx.x * 256 + threadIdx.x;
  const float* qrow = qc + ((size_t)bh * 1024 + r) * 16;
  float q[16];
#pragma unroll
  for (int c = 0; c < 16; c += 4) {
    float4 v = *(const float4*)(qrow + c);
    q[c] = v.x; q[c + 1] = v.y; q[c + 2] = v.z; q[c + 3] = v.w;
  }
  float m = -1e30f, lsum = 0.f, acc[16];
#pragma unroll
  for (int c = 0; c < 16; c++) acc[c] = 0.f;
  int jmax = blockIdx.x * 256 + 255;
  for (int j0 = 0; j0 <= jmax; j0 += 128) {
    __syncthreads();
    for (int i = threadIdx.x; i < 512; i += 256) {
      int jr = i >> 2, c4 = (i & 3) << 2;
      size_t sb = ((size_t)bh * 1024 + j0 + jr) * 16 + c4;
      *(float4*)&kcs[jr][c4] = *(const float4*)(kc + sb);
      *(float4*)&vcs[jr][c4] = *(const float4*)(vc + sb);
    }
    __syncthreads();
    int jend = min(128, r - j0 + 1);
    for (int j = 0; j < jend; j++) {
      float s = 0.f;
#pragma unroll
      for (int c = 0; c < 16; c++) s += q[c] * kcs[j][c];
      s *= 0.25f;
      if (s > m) {
        float sc = __expf(m - s);
        m = s; lsum *= sc;
#pragma unroll
        for (int c = 0; c < 16; c++) acc[c] *= sc;
      }
      float p = __expf(s - m);
      lsum += p;
#pragma unroll
      for (int c = 0; c < 16; c++) acc[c] += p * vcs[j][c];
    }
  }
  float inv = 1.f / lsum;
#pragma unroll
  for (int c = 0; c < 16; c++) acc[c] *= inv;
  int b = bh >> 4, h = bh & 15;
  size_t ob = ((size_t)(b * 1024 + r)) * 1024 + h * 64;
#pragma unroll
  for (int d = 0; d < 64; d++) {
    float s = bdc[d];
#pragma unroll
    for (int c = 0; c < 16; c++) s += acc[c] * Wdc[c * 64 + d];
    ao[ob + d] = f2bf(s);
  }
}

// ---------------- router gates + top-2 ---------------------------------------
__global__ __launch_bounds__(256) void k_gates(const float* __restrict__ h2f,
                                               const float* __restrict__ Wr,
                                               const float* __restrict__ br,
                                               int* __restrict__ eidx,
                                               float* __restrict__ ew) {
  int n = blockIdx.x, tid = threadIdx.x;
  int e = tid >> 5, i = tid & 31;
  const float* hr = h2f + (size_t)n * 1024;
  float s = 0.f;
  for (int d = i; d < 1024; d += 32) s += hr[d] * Wr[d * 8 + e];
#pragma unroll
  for (int o = 16; o; o >>= 1) s += __shfl_down(s, o, 32);
  __shared__ float gate[8];
  if (i == 0) gate[e] = s + br[e];
  __syncthreads();
  if (tid == 0) {
    float v0 = -1e30f, v1 = -1e30f; int i0 = 0, i1 = 0;
#pragma unroll
    for (int ee = 0; ee < 8; ee++) {
      float gv = gate[ee];
      if (gv > v0) { v1 = v0; i1 = i0; v0 = gv; i0 = ee; }
      else if (gv > v1) { v1 = gv; i1 = ee; }
    }
    float p0 = 1.f / (1.f + expf(v1 - v0));
    eidx[2 * n] = i0; eidx[2 * n + 1] = i1;
    ew[2 * n] = p0; ew[2 * n + 1] = 1.f - p0;
  }
}

// ---------------- routing: counting sort by expert, padded to 128 ------------
__global__ void k_route(const int* __restrict__ eidx, int* __restrict__ stok,
                        int* __restrict__ posA, int* __restrict__ tmap) {
  __shared__ int cnt[8], base[8], cur[8];
  int tid = threadIdx.x;
  if (tid < 8) { cnt[tid] = 0; cur[tid] = 0; }
  __syncthreads();
  for (int a = tid; a < 4096; a += 256) atomicAdd(&cnt[eidx[a]], 1);
  __syncthreads();
  if (tid == 0) {
    for (int tt = 0; tt < 16; tt++) tmap[tt] = 8;
    for (int tt = 16; tt < 32; tt++) tmap[tt] = 9;
    int off = 4096, t = 32;
    for (int e = 0; e < 8; e++) {
      base[e] = off;
      int nt = (cnt[e] + 127) >> 7;
      for (int k = 0; k < nt; k++) tmap[t++] = e;
      off += nt * 128;
    }
    for (; t < 72; t++) tmap[t] = -1;
  }
  __syncthreads();
  for (int r = tid; r < 4096; r += 256) stok[r] = r & 2047;
  for (int r = 4096 + tid; r < 9216; r += 256) stok[r] = 0;
  __syncthreads();
  for (int a = tid; a < 4096; a += 256) {
    int e = eidx[a];
    int p = base[e] + atomicAdd(&cur[e], 1);
    stok[p] = a >> 1;
    posA[a] = p;
  }
}

// ---------------- final combine: x2 + shared mean + weighted moe -------------
__global__ __launch_bounds__(256) void k_combine(const float* __restrict__ x2,
                                                 const float* __restrict__ oe,
                                                 const int* __restrict__ posA,
                                                 const float* __restrict__ ew,
                                                 float* __restrict__ out) {
  int n = blockIdx.x, tid = threadIdx.x;
  int c = tid * 4;
  int p0 = posA[2 * n], p1 = posA[2 * n + 1];
  float w0 = ew[2 * n], w1 = ew[2 * n + 1];
  size_t bidx = (size_t)n * 1024 + c;
  float4 r = *(const float4*)(x2 + bidx);
  float4 s0 = *(const float4*)(oe + bidx);
  float4 s1 = *(const float4*)(oe + (size_t)(2048 + n) * 1024 + c);
  float4 m0 = *(const float4*)(oe + (size_t)p0 * 1024 + c);
  float4 m1 = *(const float4*)(oe + (size_t)p1 * 1024 + c);
  float4 o;
  o.x = r.x + 0.5f * (s0.x + s1.x) + w0 * m0.x + w1 * m1.x;
  o.y = r.y + 0.5f * (s0.y + s1.y) + w0 * m0.y + w1 * m1.y;
  o.z = r.z + 0.5f * (s0.z + s1.z) + w0 * m0.z + w1 * m1.z;
  o.w = r.w + 0.5f * (s0.w + s1.w) + w0 * m0.w + w1 * m1.w;
  *(float4*)(out + bidx) = o;
}

// =============================================================================
extern "C" void kernel_launch(void* const* d_in, const int* in_sizes, int n_in,
                              void* d_out, int out_size, void* d_ws, size_t ws_size,
                              hipStream_t stream) {
  const float* x    = (const float*)d_in[0];
  const float* cosb = (const float*)d_in[1];
  const float* sinb = (const float*)d_in[2];
  const float* ln1g = (const float*)d_in[3];
  const float* ln1b = (const float*)d_in[4];
  const float* Wq   = (const float*)d_in[5];
  const float* bq   = (const float*)d_in[6];
  const float* Wk   = (const float*)d_in[7];
  const float* bk   = (const float*)d_in[8];
  const float* Wv   = (const float*)d_in[9];
  const float* bv   = (const float*)d_in[10];
  const float* Wqc  = (const float*)d_in[11];
  const float* bqc  = (const float*)d_in[12];
  const float* Wkc  = (const float*)d_in[13];
  const float* bkc  = (const float*)d_in[14];
  const float* Wvc  = (const float*)d_in[15];
  const float* bvc  = (const float*)d_in[16];
  const float* Wdc  = (const float*)d_in[17];
  const float* bdc  = (const float*)d_in[18];
  const float* Wo   = (const float*)d_in[19];
  const float* bo   = (const float*)d_in[20];
  const float* ln2g = (const float*)d_in[21];
  const float* ln2b = (const float*)d_in[22];
  const float* Wr   = (const float*)d_in[23];
  const float* br   = (const float*)d_in[24];
  const float* We1  = (const float*)d_in[25];
  const float* be1  = (const float*)d_in[26];
  const float* We2  = (const float*)d_in[27];
  const float* be2  = (const float*)d_in[28];
  const float* Ws1  = (const float*)d_in[29];
  const float* bs1  = (const float*)d_in[30];
  const float* Ws2  = (const float*)d_in[31];
  const float* bs2  = (const float*)d_in[32];

  // ---- workspace arena (total ~302 MB; heb overlays dead attention buffers)
  char* w = (char*)d_ws;
  size_t off = 0;
  auto alloc = [&](size_t bytes) -> void* {
    off = (off + 255) & ~(size_t)255;
    void* p = w + off;
    off += bytes;
    return p;
  };
  u16*   W1a  = (u16*)alloc(10ull * 4096 * 1024 * 2);   // 80 MiB
  u16*   W2a  = (u16*)alloc(10ull * 4096 * 1024 * 2);   // 80 MiB
  float* b1a  = (float*)alloc(10 * 4096 * 4);
  float* b2a  = (float*)alloc(10 * 1024 * 4);
  float* bqkv = (float*)alloc(3072 * 4);
  float* x2b  = (float*)alloc(2048ull * 1024 * 4);
  u16*   h2b  = (u16*)alloc(2048ull * 1024 * 2);
  float* h2f  = (float*)alloc(2048ull * 1024 * 4);
  int*   eidx = (int*)alloc(4096 * 4);
  float* ew   = (float*)alloc(4096 * 4);
  int*   posA = (int*)alloc(4096 * 4);
  int*   stok = (int*)alloc(9216 * 4);
  int*   tmap = (int*)alloc(72 * 4);
  float* oeb  = (float*)alloc(9216ull * 1024 * 4);      // 36 MiB
  char*  R    = (char*)alloc(9216ull * 4096 * 2);       // 72 MiB region
  // heb owns R during the MoE phase; attention-phase buffers overlay R and are
  // all dead before the first MoE GEMM writes heb.
  u16*   heb  = (u16*)R;
  u16*   WT   = (u16*)(R);                               //  8 MiB (4x 1Kx1K)
  u16*   hbuf = (u16*)(R + 8388608);                     //  4 MiB
  u16*   qkvb = (u16*)(R + 8388608 + 4194304);           // 12 MiB
  float* qcb  = (float*)(R + 25165824);                  //  2 MiB
  float* kcb  = (float*)(R + 27262976);                  //  2 MiB
  float* vcb  = (float*)(R + 29360128);                  //  2 MiB
  u16*   aob  = (u16*)(R + 31457280);                    //  4 MiB (ends 35.7M < 72M)
  (void)ws_size; (void)in_sizes; (void)n_in; (void)out_size;

  // weight conversion (re-done every call: harness re-poisons ws)
  k_trans4   <<<dim3(32, 32, 4),  dim3(32, 8), 0, stream>>>(Wq, Wk, Wv, Wo, WT);
  k_trans_exp<<<dim3(32, 128, 10), dim3(32, 8), 0, stream>>>(We1, Ws1, W1a, 1024, 4096);
  k_trans_exp<<<dim3(128, 32, 10), dim3(32, 8), 0, stream>>>(We2, Ws2, W2a, 4096, 1024);
  k_bias     <<<212, 256, 0, stream>>>(be1, bs1, be2, bs2, bq, bk, bv, b1a, b2a, bqkv);

  // attention path
  k_ln<<<2048, 256, 0, stream>>>(x, ln1g, ln1b, hbuf, nullptr);
  k_gemm<0, false, false><<<dim3(16, 24), 256, 0, stream>>>(hbuf, WT, bqkv, qkvb, nullptr, 3072, 1024, nullptr, nullptr);
  k_ropec<<<dim3(2048, 1, 3), 256, 0, stream>>>(qkvb, cosb, sinb,
                                                Wqc, bqc, Wkc, bkc, Wvc, bvc, qcb, kcb, vcb);
  k_attn<<<dim3(4, 32), 256, 0, stream>>>(qcb, kcb, vcb, Wdc, bdc, aob);
  k_gemm<1, false, false><<<dim3(16, 8), 256, 0, stream>>>(aob, WT + 3145728, bo, x2b, x, 1024, 1024, nullptr, nullptr);

  // FFN path
  k_ln<<<2048, 256, 0, stream>>>(x2b, ln2g, ln2b, h2b, h2f);
  k_gates<<<2048, 256, 0, stream>>>(h2f, Wr, br, eidx, ew);
  k_route<<<1, 256, 0, stream>>>(eidx, stok, posA, tmap);
  k_gemm<2, true, true ><<<dim3(72, 32), 256, 0, stream>>>(h2b, W1a, b1a, heb, nullptr, 4096, 1024, tmap, stok);
  k_gemm<3, true, false><<<dim3(72, 8),  256, 0, stream>>>(heb, W2a, b2a, oeb, nullptr, 1024, 4096, tmap, nullptr);
  k_combine<<<2048, 256, 0, stream>>>(x2b, oeb, posA, ew, (float*)d_out);
}